// Round 1
// 1761.392 us; speedup vs baseline: 1.0279x; 1.0279x over previous
//
#include <hip/hip_runtime.h>
#include <hip/hip_bf16.h>
#include <hip/hip_cooperative_groups.h>
#include <type_traits>

namespace cg = cooperative_groups;

// Grid restructure (R1): 256 blocks = 2 blocks per batch (axis-split), cooperative
// launch with grid syncs. Each block keeps a private LDS copy of h, computes ONE
// axial-attention phase per layer, exchanges the 18432-float phase output through
// the d_ws workspace (L2-resident), and both blocks apply the identical
// h = relu(o_row + o_col) update (fp32 add is commutative -> h stays bitwise
// identical across the pair; numerics unchanged vs the single-block kernel).
#define BDIM 1024
#define NBLK 256
#define NBAT 128
#define SS   48
#define DD   8
#define HDIM 8
#define NL   8
#define NC   7
#define NWAV (BDIM/64)          // 16 waves/block
#define PPW  (SS/NWAV)          // 3 serial problems per wave
// LDS layout [i][d][j]: offset = i*RS + d*SS + j.  RS odd => both access
// orientations (lane-stride RS and lane-stride 1) are conflict-free.
#define RS   385
#define HSZ  (SS*RS)            // 18480 floats per buffer
#define GST  (SS*SS*DD)         // 18432 floats per block's exchange region
#define SMEM_FLOATS (2*HSZ + 264 + 784 + 8)
#define SMEM_BYTES  (SMEM_FLOATS*4)   // 152,064 B -> 1 block/CU

__device__ __forceinline__ float l2f(const float v)           { return v; }
__device__ __forceinline__ float l2f(const __hip_bfloat16 v)  { return __bfloat162float(v); }
__device__ __forceinline__ void  stf(float* p, float v)          { *p = v; }
__device__ __forceinline__ void  stf(__hip_bfloat16* p, float v) { *p = __float2bfloat16(v); }
__device__ __forceinline__ float rl(float v, int l) {
    return __int_as_float(__builtin_amdgcn_readlane(__float_as_int(v), l));
}

// One axial-attention phase over LDS-resident state; always writes its
// (pre-activation, bias-included) output into ab at the canonical [i][d][j] slot.
// COLPHASE=0: problems are columns, tokens are rows (row attention).
// COLPHASE=1: problems are rows, tokens are cols (col attention).
// wb layout: [0,64) Wq, [64,128) Wk, [128,192) Wv, [192,256) Wo, [256,264) bo.
template <int COLPHASE>
__device__ __attribute__((noinline))
void attn_phase(const float* __restrict__ hb, float* __restrict__ ab,
                const float* __restrict__ wb, int wav, int lane, int tl)
{
    #pragma unroll 1
    for (int p = 0; p < PPW; ++p) {
        const int prob = wav + p*NWAV;
        const int base = COLPHASE ? (prob*RS + tl) : (tl*RS + prob);

        float ht[DD];
        #pragma unroll
        for (int d = 0; d < DD; ++d) ht[d] = hb[base + d*SS];

        // q/k/v projections; fold 0.5 (E^-0.5) * log2(e) into q for exp2.
        float q[HDIM], k[HDIM], v[HDIM];
        #pragma unroll
        for (int o = 0; o < HDIM; ++o) {
            float aq = 0.f, ak = 0.f, av = 0.f;
            #pragma unroll
            for (int d = 0; d < DD; ++d) {
                aq += ht[d] * wb[o*8 + d];
                ak += ht[d] * wb[64 + o*8 + d];
                av += ht[d] * wb[128 + o*8 + d];
            }
            q[o] = aq * 0.72134752044f;  // 0.5 * log2(e)
            k[o] = ak; v[o] = av;
        }

        float ov[HDIM];
        #pragma unroll
        for (int hh = 0; hh < 2; ++hh) {
            float dt[SS];
            #pragma unroll
            for (int j2 = 0; j2 < SS; ++j2) {
                float acc =  q[hh*4+0] * rl(k[hh*4+0], j2);
                acc       += q[hh*4+1] * rl(k[hh*4+1], j2);
                acc       += q[hh*4+2] * rl(k[hh*4+2], j2);
                acc       += q[hh*4+3] * rl(k[hh*4+3], j2);
                dt[j2] = acc;
            }
            float m = dt[0];
            #pragma unroll
            for (int j2 = 1; j2 < SS; ++j2) m = fmaxf(m, dt[j2]);
            float s = 0.f;
            #pragma unroll
            for (int j2 = 0; j2 < SS; ++j2) {
                float pv = exp2f(dt[j2] - m);
                dt[j2] = pv; s += pv;
            }
            float o0 = 0.f, o1 = 0.f, o2 = 0.f, o3 = 0.f;
            #pragma unroll
            for (int j2 = 0; j2 < SS; ++j2) {
                float pv = dt[j2];
                o0 += pv * rl(v[hh*4+0], j2);
                o1 += pv * rl(v[hh*4+1], j2);
                o2 += pv * rl(v[hh*4+2], j2);
                o3 += pv * rl(v[hh*4+3], j2);
            }
            float rs = 1.f / s;
            ov[hh*4+0] = o0*rs; ov[hh*4+1] = o1*rs;
            ov[hh*4+2] = o2*rs; ov[hh*4+3] = o3*rs;
        }

        if (lane < SS) {
            #pragma unroll
            for (int d = 0; d < DD; ++d) {
                float acc = wb[256 + d];
                #pragma unroll
                for (int o2 = 0; o2 < HDIM; ++o2) acc += ov[o2] * wb[192 + d*8 + o2];
                ab[base + d*SS] = acc;
            }
        }
    }
}

template <typename T>
__global__ void __launch_bounds__(BDIM, 4)   // 4 waves/EU -> VGPR cap 128 (16-wave block must fit 1/CU)
axial_kernel(const void* xv, const void* enc_wv, const void* enc_bv,
             const void* pos_rowv, const void* pos_colv,
             const void* Wqv, const void* Wkv, const void* Wvv, const void* Wov,
             const void* bov, const void* cls_wv, const void* cls_bv,
             void* outv, void* wsv)
{
    // dtype sniff on x (robustness): low 16 bits of each dword are a plausible
    // bf16 exponent iff data is bf16-packed; random mantissa bits if fp32.
    const unsigned* xu = (const unsigned*)xv;
    int cnt = 0;
    #pragma unroll
    for (int t = 0; t < 32; ++t) {
        const unsigned w = xu[t];
        const int e = (w >> 7) & 0xff;
        cnt += (e > 100 && e < 150) ? 1 : 0;
    }
    const bool isbf = (cnt >= 20);
    constexpr bool wantbf = std::is_same<T, __hip_bfloat16>::value;
    if (isbf != wantbf) return;   // wrong-dtype instantiation: no-op

    cg::grid_group grid = cg::this_grid();

    const T* x       = (const T*)xv;
    const T* enc_w   = (const T*)enc_wv;
    const T* enc_b   = (const T*)enc_bv;
    const T* pos_row = (const T*)pos_rowv;
    const T* pos_col = (const T*)pos_colv;
    const T* Wq      = (const T*)Wqv;
    const T* Wk      = (const T*)Wkv;
    const T* Wv      = (const T*)Wvv;
    const T* Wo      = (const T*)Wov;
    const T* bo      = (const T*)bov;
    const T* cls_w   = (const T*)cls_wv;
    const T* cls_b   = (const T*)cls_bv;
    T*       out     = (T*)outv;
    float*   G       = (float*)wsv;     // NBLK * GST floats = 18.9 MB exchange buffer

    extern __shared__ float smem[];
    float* hb = smem;              // h image           [HSZ]
    float* ab = hb + HSZ;          // own phase output  [HSZ]
    float* wb = ab + HSZ;          // layer weights (own axis) [264]
    float* eb = wb + 264;          // enc_w/enc_b/pos_row/pos_col [784]
    float* cb = eb + 784;          // classifier logits [8]

    const int bid   = blockIdx.x;
    const int batch = bid & (NBAT-1);
    const int axis  = bid >> 7;            // partner = bid ^ 128 (same XCD mod 8)
    const int tid   = threadIdx.x;
    const int lane  = tid & 63;
    const int wav   = tid >> 6;
    const int tl    = lane < SS ? lane : SS-1;

    float* Gmine = G + (size_t)bid * GST;
    const float* Gpart = G + (size_t)(bid ^ NBAT) * GST;

    // stage encoder/pos params
    for (int f = tid; f < 784; f += BDIM) {
        float v;
        if (f < 8)        v = l2f(enc_w[f]);
        else if (f < 16)  v = l2f(enc_b[f-8]);
        else if (f < 400) v = l2f(pos_row[f-16]);
        else              v = l2f(pos_col[f-400]);
        eb[f] = v;
    }
    __syncthreads();

    // encoder: h = relu(x*enc_w + enc_b) + pos_row[i] + pos_col[j]
    // (both partner blocks compute identical h)
    const T* xb = x + (size_t)batch * SS * SS;
    for (int p = tid; p < SS*SS; p += BDIM) {
        const int i = p / SS, j = p % SS;
        const float xv2 = l2f(xb[p]);
        #pragma unroll
        for (int d = 0; d < DD; ++d) {
            float hv = fmaxf(0.f, xv2*eb[d] + eb[8+d]) + eb[16 + i*8 + d] + eb[400 + j*8 + d];
            hb[i*RS + d*SS + j] = hv;
        }
    }

    #pragma unroll 1
    for (int l = 0; l < NL; ++l) {
        __syncthreads();                     // hb update / prior wb reads complete
        const int la = l*2 + axis;
        for (int f = tid; f < 264; f += BDIM) {
            float v;
            if (f < 64)       v = l2f(Wq[la*64 + f]);
            else if (f < 128) v = l2f(Wk[la*64 + f-64]);
            else if (f < 192) v = l2f(Wv[la*64 + f-128]);
            else if (f < 256) v = l2f(Wo[la*64 + f-192]);
            else              v = l2f(bo[la*8 + f-256]);
            wb[f] = v;
        }
        __syncthreads();

        if (axis == 0) attn_phase<0>(hb, ab, wb, wav, lane, tl);   // o_row -> ab
        else           attn_phase<1>(hb, ab, wb, wav, lane, tl);   // o_col -> ab
        __syncthreads();                     // ab complete

        // stage ab -> G[bid] coalesced ([pixel][d] layout, float4 x2 per pixel)
        for (int p = tid; p < SS*SS; p += BDIM) {
            const int i = p / SS, j = p % SS, base = i*RS + j;
            float4 v0, v1;
            v0.x = ab[base     ]; v0.y = ab[base+  SS]; v0.z = ab[base+2*SS]; v0.w = ab[base+3*SS];
            v1.x = ab[base+4*SS]; v1.y = ab[base+5*SS]; v1.z = ab[base+6*SS]; v1.w = ab[base+7*SS];
            float4* gp = reinterpret_cast<float4*>(Gmine + (size_t)p * DD);
            gp[0] = v0; gp[1] = v1;
        }
        grid.sync();                         // partner's output now visible

        if (l == NL-1 && axis == 1) return;  // col block done after last exchange

        // h = relu(own + partner)  (commutative -> bitwise identical across pair)
        for (int p = tid; p < SS*SS; p += BDIM) {
            const int i = p / SS, j = p % SS, base = i*RS + j;
            const float4* gp = reinterpret_cast<const float4*>(Gpart + (size_t)p * DD);
            const float4 g0 = gp[0], g1 = gp[1];
            hb[base     ] = fmaxf(0.f, ab[base     ] + g0.x);
            hb[base+  SS] = fmaxf(0.f, ab[base+  SS] + g0.y);
            hb[base+2*SS] = fmaxf(0.f, ab[base+2*SS] + g0.z);
            hb[base+3*SS] = fmaxf(0.f, ab[base+3*SS] + g0.w);
            hb[base+4*SS] = fmaxf(0.f, ab[base+4*SS] + g1.x);
            hb[base+5*SS] = fmaxf(0.f, ab[base+5*SS] + g1.y);
            hb[base+6*SS] = fmaxf(0.f, ab[base+6*SS] + g1.z);
            hb[base+7*SS] = fmaxf(0.f, ab[base+7*SS] + g1.w);
        }
        if (l < NL-1) grid.sync();           // G[bid] safe to overwrite next layer
    }
    __syncthreads();                         // only axis==0 blocks reach here

    // max over d -> ab[p] (flat reuse)
    for (int p = tid; p < SS*SS; p += BDIM) {
        const int i = p / SS, j = p % SS;
        float mv = hb[i*RS + j];
        #pragma unroll
        for (int d = 1; d < DD; ++d) mv = fmaxf(mv, hb[i*RS + d*SS + j]);
        ab[p] = mv;
    }
    if (tid < NC) cb[tid] = l2f(cls_b[tid]);
    __syncthreads();

    float part[NC] = {0.f,0.f,0.f,0.f,0.f,0.f,0.f};
    for (int p = tid; p < SS*SS; p += BDIM) {
        const float mv = ab[p];
        #pragma unroll
        for (int c = 0; c < NC; ++c) part[c] += mv * l2f(cls_w[c*(SS*SS) + p]);
    }
    #pragma unroll
    for (int c = 0; c < NC; ++c) {
        #pragma unroll
        for (int off = 32; off > 0; off >>= 1) part[c] += __shfl_down(part[c], off, 64);
    }
    if (lane == 0) {
        #pragma unroll
        for (int c = 0; c < NC; ++c) atomicAdd(&cb[c], part[c]);
    }
    __syncthreads();

    if (tid < NC) {
        float m = cb[0];
        #pragma unroll
        for (int c = 1; c < NC; ++c) m = fmaxf(m, cb[c]);
        float s = 0.f;
        #pragma unroll
        for (int c = 0; c < NC; ++c) s += exp2f((cb[c]-m) * 1.44269504089f);
        const float e = exp2f((cb[tid]-m) * 1.44269504089f);
        stf(&out[batch*NC + tid], e / s);
    }
}

extern "C" void kernel_launch(void* const* d_in, const int* in_sizes, int n_in,
                              void* d_out, int out_size, void* d_ws, size_t ws_size,
                              hipStream_t stream) {
    (void)in_sizes; (void)n_in; (void)ws_size; (void)out_size;
    hipFuncSetAttribute(reinterpret_cast<const void*>(&axial_kernel<float>),
                        hipFuncAttributeMaxDynamicSharedMemorySize, SMEM_BYTES);
    hipFuncSetAttribute(reinterpret_cast<const void*>(&axial_kernel<__hip_bfloat16>),
                        hipFuncAttributeMaxDynamicSharedMemorySize, SMEM_BYTES);

    void* ins[12];
    for (int i = 0; i < 12; ++i) ins[i] = d_in[i];
    void* args[14];
    for (int i = 0; i < 12; ++i) args[i] = &ins[i];
    args[12] = &d_out;
    args[13] = &d_ws;     // needs NBLK*GST*4 = 18.9 MB workspace

    hipLaunchCooperativeKernel(reinterpret_cast<const void*>(&axial_kernel<float>),
                               dim3(NBLK), dim3(BDIM), args, (unsigned)SMEM_BYTES, stream);
    hipLaunchCooperativeKernel(reinterpret_cast<const void*>(&axial_kernel<__hip_bfloat16>),
                               dim3(NBLK), dim3(BDIM), args, (unsigned)SMEM_BYTES, stream);
}

// Round 2
// 1534.312 us; speedup vs baseline: 1.1801x; 1.1480x over previous
//
#include <hip/hip_runtime.h>
#include <hip/hip_bf16.h>
#include <hip/hip_cooperative_groups.h>
#include <type_traits>

namespace cg = cooperative_groups;

// R2: keep R1's axis-split cooperative structure (2 blocks/batch, 256 blocks,
// grid-sync exchange through d_ws), but revert the block to 512 threads.
// R1's 1024-thread block got a 64-VGPR cap from the toolchain (observed
// VGPR_Count 64 vs 124 at 512 threads) -> dt[48] spilled -> ~2 GB/dispatch of
// scratch traffic (FETCH 927MB / WRITE 1.14GB) and no speedup. 512-thread
// blocks are the proven-no-spill shape (R0: 124 VGPR, cap 128).
#define BDIM 512
#define NBLK 256
#define NBAT 128
#define SS   48
#define DD   8
#define HDIM 8
#define NL   8
#define NC   7
#define NWAV (BDIM/64)          // 8 waves/block
#define PPW  (SS/NWAV)          // 6 serial problems per wave
// LDS layout [i][d][j]: offset = i*RS + d*SS + j.  RS odd => both access
// orientations (lane-stride RS and lane-stride 1) are conflict-free.
#define RS   385
#define HSZ  (SS*RS)            // 18480 floats per buffer
#define GST  (SS*SS*DD)         // 18432 floats per block's exchange region
#define SMEM_FLOATS (2*HSZ + 264 + 784 + 8)
#define SMEM_BYTES  (SMEM_FLOATS*4)   // 152,064 B -> 1 block/CU

__device__ __forceinline__ float l2f(const float v)           { return v; }
__device__ __forceinline__ float l2f(const __hip_bfloat16 v)  { return __bfloat162float(v); }
__device__ __forceinline__ void  stf(float* p, float v)          { *p = v; }
__device__ __forceinline__ void  stf(__hip_bfloat16* p, float v) { *p = __float2bfloat16(v); }
__device__ __forceinline__ float rl(float v, int l) {
    return __int_as_float(__builtin_amdgcn_readlane(__float_as_int(v), l));
}

// One axial-attention phase over LDS-resident state; writes its
// (pre-activation, bias-included) output into ab at the canonical [i][d][j] slot.
// COLPHASE=0: problems are columns, tokens are rows (row attention).
// COLPHASE=1: problems are rows, tokens are cols (col attention).
// wb layout: [0,64) Wq, [64,128) Wk, [128,192) Wv, [192,256) Wo, [256,264) bo.
template <int COLPHASE>
__device__ __attribute__((noinline))
void attn_phase(const float* __restrict__ hb, float* __restrict__ ab,
                const float* __restrict__ wb, int wav, int lane, int tl)
{
    #pragma unroll 1
    for (int p = 0; p < PPW; ++p) {
        const int prob = wav + p*NWAV;
        const int base = COLPHASE ? (prob*RS + tl) : (tl*RS + prob);

        float ht[DD];
        #pragma unroll
        for (int d = 0; d < DD; ++d) ht[d] = hb[base + d*SS];

        // q/k/v projections; fold 0.5 (E^-0.5) * log2(e) into q for exp2.
        float q[HDIM], k[HDIM], v[HDIM];
        #pragma unroll
        for (int o = 0; o < HDIM; ++o) {
            float aq = 0.f, ak = 0.f, av = 0.f;
            #pragma unroll
            for (int d = 0; d < DD; ++d) {
                aq += ht[d] * wb[o*8 + d];
                ak += ht[d] * wb[64 + o*8 + d];
                av += ht[d] * wb[128 + o*8 + d];
            }
            q[o] = aq * 0.72134752044f;  // 0.5 * log2(e)
            k[o] = ak; v[o] = av;
        }

        float ov[HDIM];
        #pragma unroll
        for (int hh = 0; hh < 2; ++hh) {
            float dt[SS];
            #pragma unroll
            for (int j2 = 0; j2 < SS; ++j2) {
                float acc =  q[hh*4+0] * rl(k[hh*4+0], j2);
                acc       += q[hh*4+1] * rl(k[hh*4+1], j2);
                acc       += q[hh*4+2] * rl(k[hh*4+2], j2);
                acc       += q[hh*4+3] * rl(k[hh*4+3], j2);
                dt[j2] = acc;
            }
            float m = dt[0];
            #pragma unroll
            for (int j2 = 1; j2 < SS; ++j2) m = fmaxf(m, dt[j2]);
            float s = 0.f;
            #pragma unroll
            for (int j2 = 0; j2 < SS; ++j2) {
                float pv = exp2f(dt[j2] - m);
                dt[j2] = pv; s += pv;
            }
            float o0 = 0.f, o1 = 0.f, o2 = 0.f, o3 = 0.f;
            #pragma unroll
            for (int j2 = 0; j2 < SS; ++j2) {
                float pv = dt[j2];
                o0 += pv * rl(v[hh*4+0], j2);
                o1 += pv * rl(v[hh*4+1], j2);
                o2 += pv * rl(v[hh*4+2], j2);
                o3 += pv * rl(v[hh*4+3], j2);
            }
            float rs = 1.f / s;
            ov[hh*4+0] = o0*rs; ov[hh*4+1] = o1*rs;
            ov[hh*4+2] = o2*rs; ov[hh*4+3] = o3*rs;
        }

        if (lane < SS) {
            #pragma unroll
            for (int d = 0; d < DD; ++d) {
                float acc = wb[256 + d];
                #pragma unroll
                for (int o2 = 0; o2 < HDIM; ++o2) acc += ov[o2] * wb[192 + d*8 + o2];
                ab[base + d*SS] = acc;
            }
        }
    }
}

template <typename T>
__global__ void __launch_bounds__(BDIM, 1)   // 512 threads -> VGPR cap 128 (proven 124-alloc, no spill)
axial_kernel(const void* xv, const void* enc_wv, const void* enc_bv,
             const void* pos_rowv, const void* pos_colv,
             const void* Wqv, const void* Wkv, const void* Wvv, const void* Wov,
             const void* bov, const void* cls_wv, const void* cls_bv,
             void* outv, void* wsv)
{
    // dtype sniff on x (robustness): low 16 bits of each dword are a plausible
    // bf16 exponent iff data is bf16-packed; random mantissa bits if fp32.
    const unsigned* xu = (const unsigned*)xv;
    int cnt = 0;
    #pragma unroll
    for (int t = 0; t < 32; ++t) {
        const unsigned w = xu[t];
        const int e = (w >> 7) & 0xff;
        cnt += (e > 100 && e < 150) ? 1 : 0;
    }
    const bool isbf = (cnt >= 20);
    constexpr bool wantbf = std::is_same<T, __hip_bfloat16>::value;
    if (isbf != wantbf) return;   // wrong-dtype instantiation: no-op

    cg::grid_group grid = cg::this_grid();

    const T* x       = (const T*)xv;
    const T* enc_w   = (const T*)enc_wv;
    const T* enc_b   = (const T*)enc_bv;
    const T* pos_row = (const T*)pos_rowv;
    const T* pos_col = (const T*)pos_colv;
    const T* Wq      = (const T*)Wqv;
    const T* Wk      = (const T*)Wkv;
    const T* Wv      = (const T*)Wvv;
    const T* Wo      = (const T*)Wov;
    const T* bo      = (const T*)bov;
    const T* cls_w   = (const T*)cls_wv;
    const T* cls_b   = (const T*)cls_bv;
    T*       out     = (T*)outv;
    float*   G       = (float*)wsv;     // NBLK * GST floats = 18.9 MB exchange buffer

    extern __shared__ float smem[];
    float* hb = smem;              // h image           [HSZ]
    float* ab = hb + HSZ;          // own phase output  [HSZ]
    float* wb = ab + HSZ;          // layer weights (own axis) [264]
    float* eb = wb + 264;          // enc_w/enc_b/pos_row/pos_col [784]
    float* cb = eb + 784;          // classifier logits [8]

    const int bid   = blockIdx.x;
    const int batch = bid & (NBAT-1);
    const int axis  = bid >> 7;            // partner = bid ^ 128 (same XCD mod 8)
    const int tid   = threadIdx.x;
    const int lane  = tid & 63;
    const int wav   = tid >> 6;
    const int tl    = lane < SS ? lane : SS-1;

    float* Gmine = G + (size_t)bid * GST;
    const float* Gpart = G + (size_t)(bid ^ NBAT) * GST;

    // stage encoder/pos params
    for (int f = tid; f < 784; f += BDIM) {
        float v;
        if (f < 8)        v = l2f(enc_w[f]);
        else if (f < 16)  v = l2f(enc_b[f-8]);
        else if (f < 400) v = l2f(pos_row[f-16]);
        else              v = l2f(pos_col[f-400]);
        eb[f] = v;
    }
    __syncthreads();

    // encoder: h = relu(x*enc_w + enc_b) + pos_row[i] + pos_col[j]
    // (both partner blocks compute identical h)
    const T* xb = x + (size_t)batch * SS * SS;
    for (int p = tid; p < SS*SS; p += BDIM) {
        const int i = p / SS, j = p % SS;
        const float xv2 = l2f(xb[p]);
        #pragma unroll
        for (int d = 0; d < DD; ++d) {
            float hv = fmaxf(0.f, xv2*eb[d] + eb[8+d]) + eb[16 + i*8 + d] + eb[400 + j*8 + d];
            hb[i*RS + d*SS + j] = hv;
        }
    }

    #pragma unroll 1
    for (int l = 0; l < NL; ++l) {
        __syncthreads();                     // hb update / prior wb reads complete
        const int la = l*2 + axis;
        for (int f = tid; f < 264; f += BDIM) {
            float v;
            if (f < 64)       v = l2f(Wq[la*64 + f]);
            else if (f < 128) v = l2f(Wk[la*64 + f-64]);
            else if (f < 192) v = l2f(Wv[la*64 + f-128]);
            else if (f < 256) v = l2f(Wo[la*64 + f-192]);
            else              v = l2f(bo[la*8 + f-256]);
            wb[f] = v;
        }
        __syncthreads();

        if (axis == 0) attn_phase<0>(hb, ab, wb, wav, lane, tl);   // o_row -> ab
        else           attn_phase<1>(hb, ab, wb, wav, lane, tl);   // o_col -> ab
        __syncthreads();                     // ab complete

        // stage ab -> G[bid] coalesced ([pixel][d] layout, float4 x2 per pixel)
        for (int p = tid; p < SS*SS; p += BDIM) {
            const int i = p / SS, j = p % SS, base = i*RS + j;
            float4 v0, v1;
            v0.x = ab[base     ]; v0.y = ab[base+  SS]; v0.z = ab[base+2*SS]; v0.w = ab[base+3*SS];
            v1.x = ab[base+4*SS]; v1.y = ab[base+5*SS]; v1.z = ab[base+6*SS]; v1.w = ab[base+7*SS];
            float4* gp = reinterpret_cast<float4*>(Gmine + (size_t)p * DD);
            gp[0] = v0; gp[1] = v1;
        }
        grid.sync();                         // partner's output now visible

        if (l == NL-1 && axis == 1) return;  // col block done after last exchange

        // h = relu(own + partner)  (commutative -> bitwise identical across pair)
        for (int p = tid; p < SS*SS; p += BDIM) {
            const int i = p / SS, j = p % SS, base = i*RS + j;
            const float4* gp = reinterpret_cast<const float4*>(Gpart + (size_t)p * DD);
            const float4 g0 = gp[0], g1 = gp[1];
            hb[base     ] = fmaxf(0.f, ab[base     ] + g0.x);
            hb[base+  SS] = fmaxf(0.f, ab[base+  SS] + g0.y);
            hb[base+2*SS] = fmaxf(0.f, ab[base+2*SS] + g0.z);
            hb[base+3*SS] = fmaxf(0.f, ab[base+3*SS] + g0.w);
            hb[base+4*SS] = fmaxf(0.f, ab[base+4*SS] + g1.x);
            hb[base+5*SS] = fmaxf(0.f, ab[base+5*SS] + g1.y);
            hb[base+6*SS] = fmaxf(0.f, ab[base+6*SS] + g1.z);
            hb[base+7*SS] = fmaxf(0.f, ab[base+7*SS] + g1.w);
        }
        if (l < NL-1) grid.sync();           // G[bid] safe to overwrite next layer
    }
    __syncthreads();                         // only axis==0 blocks reach here

    // max over d -> ab[p] (flat reuse)
    for (int p = tid; p < SS*SS; p += BDIM) {
        const int i = p / SS, j = p % SS;
        float mv = hb[i*RS + j];
        #pragma unroll
        for (int d = 1; d < DD; ++d) mv = fmaxf(mv, hb[i*RS + d*SS + j]);
        ab[p] = mv;
    }
    if (tid < NC) cb[tid] = l2f(cls_b[tid]);
    __syncthreads();

    float part[NC] = {0.f,0.f,0.f,0.f,0.f,0.f,0.f};
    for (int p = tid; p < SS*SS; p += BDIM) {
        const float mv = ab[p];
        #pragma unroll
        for (int c = 0; c < NC; ++c) part[c] += mv * l2f(cls_w[c*(SS*SS) + p]);
    }
    #pragma unroll
    for (int c = 0; c < NC; ++c) {
        #pragma unroll
        for (int off = 32; off > 0; off >>= 1) part[c] += __shfl_down(part[c], off, 64);
    }
    if (lane == 0) {
        #pragma unroll
        for (int c = 0; c < NC; ++c) atomicAdd(&cb[c], part[c]);
    }
    __syncthreads();

    if (tid < NC) {
        float m = cb[0];
        #pragma unroll
        for (int c = 1; c < NC; ++c) m = fmaxf(m, cb[c]);
        float s = 0.f;
        #pragma unroll
        for (int c = 0; c < NC; ++c) s += exp2f((cb[c]-m) * 1.44269504089f);
        const float e = exp2f((cb[tid]-m) * 1.44269504089f);
        stf(&out[batch*NC + tid], e / s);
    }
}

extern "C" void kernel_launch(void* const* d_in, const int* in_sizes, int n_in,
                              void* d_out, int out_size, void* d_ws, size_t ws_size,
                              hipStream_t stream) {
    (void)in_sizes; (void)n_in; (void)ws_size; (void)out_size;
    hipFuncSetAttribute(reinterpret_cast<const void*>(&axial_kernel<float>),
                        hipFuncAttributeMaxDynamicSharedMemorySize, SMEM_BYTES);
    hipFuncSetAttribute(reinterpret_cast<const void*>(&axial_kernel<__hip_bfloat16>),
                        hipFuncAttributeMaxDynamicSharedMemorySize, SMEM_BYTES);

    void* ins[12];
    for (int i = 0; i < 12; ++i) ins[i] = d_in[i];
    void* args[14];
    for (int i = 0; i < 12; ++i) args[i] = &ins[i];
    args[12] = &d_out;
    args[13] = &d_ws;     // needs NBLK*GST*4 = 18.9 MB workspace

    hipLaunchCooperativeKernel(reinterpret_cast<const void*>(&axial_kernel<float>),
                               dim3(NBLK), dim3(BDIM), args, (unsigned)SMEM_BYTES, stream);
    hipLaunchCooperativeKernel(reinterpret_cast<const void*>(&axial_kernel<__hip_bfloat16>),
                               dim3(NBLK), dim3(BDIM), args, (unsigned)SMEM_BYTES, stream);
}